// Round 16
// baseline (220.766 us; speedup 1.0000x reference)
//
#include <hip/hip_runtime.h>
#include <cstdint>
#include <cstddef>

#define DI __device__ __forceinline__

using f32x4  = __attribute__((ext_vector_type(4))) float;
using bf16x8 = __attribute__((ext_vector_type(8))) short;
using u32x2  = __attribute__((ext_vector_type(2))) unsigned int;
using u32x4  = __attribute__((ext_vector_type(4))) unsigned int;

constexpr int NT = 16384;   // tokens
constexpr int NF = 4096;    // features
constexpr int SLICE = 8192; // tokens per ks1/ks2 interleave slice

// y layout: PLAIN TOKEN-MAJOR y[t][b*64+d] bf16 (byte = t*8192 + b*128 + d*2).
// ks1 writes 16B d-chunks; each 128B line assembled by the 8 dg-sibling blocks
// (same XCD via swizzle) — the only write pattern measured clean (r2: 131MB).
// ks2 reads 64B-dense: y[t][a*64+kh*32+lq*8] per lane.

// fp32 -> bf16 round-to-nearest-even
DI unsigned short f2bf(float f) {
  union { float f; unsigned u; } v; v.f = f;
  unsigned u = v.u;
  u += 0x7fffu + ((u >> 16) & 1u);
  return (unsigned short)(u >> 16);
}

// ---------------- prep: factor transpose + bf16 cast (verified r2) ----------------
__global__ void ks_prep(const float* __restrict__ f0, const float* __restrict__ f1,
                        unsigned short* __restrict__ f0s, unsigned short* __restrict__ f1s) {
  int tid = blockIdx.x * 256 + threadIdx.x;     // grid covers 2*262144
  if (tid < 262144) {
    int d = tid & 63, c = (tid >> 6) & 63, b = tid >> 12;
    f0s[d * 4096 + b * 64 + c] = f2bf(f0[tid]);
  } else {
    int t2 = tid - 262144;
    f1s[t2] = f2bf(f1[t2]);
  }
}

// ---------------- stage 1 v11: r14 machinery verbatim; token-major y stores --------
// block: 128 tokens x 8 d-planes; wave wv owns d = dg*8+wv, f0 slice persistent.
// Ybuf: byte = t*1044 + dloc*128 + b*2 (u32x2 writes exact 2-way, free)
__global__ __launch_bounds__(512, 4) void ks1(
    const float* __restrict__ x, const unsigned short* __restrict__ f0s,
    unsigned short* __restrict__ yp, int tbase)
{
  __shared__ __align__(16) char L[32768 + 2 * 16704];
  char* const Xb0 = L;
  char* const Xb1 = L + 16384;
  char* const Yb0 = L + 32768;
  char* const Yb1 = L + 32768 + 16704;

  const int w  = blockIdx.x;                  // 0..511 per slice
  const int tt = (w & 7) | ((w >> 6) << 3);   // siblings (dg 0..7) share XCD
  const int dg = (w >> 3) & 7;
  const long T0 = (long)tbase + (long)tt * 128;

  const int tid = threadIdx.x, lane = tid & 63, wv = tid >> 6;
  const int l15 = lane & 15, lq = lane >> 4;
  const int d = dg * 8 + wv;

  bf16x8 fA[4][2];
  #pragma unroll
  for (int bt = 0; bt < 4; ++bt)
    #pragma unroll
    for (int kh = 0; kh < 2; ++kh)
      fA[bt][kh] = *(const bf16x8*)(f0s + (size_t)d * 4096 + (bt * 16 + l15) * 64 + kh * 32 + lq * 8);

  const int st_t = tid >> 5, st_c0 = (tid >> 1) & 15, st_dq = tid & 1;
  const float* const xrow0 = x + (T0 + st_t) * (long)NF + dg * 8 + st_dq * 4;
  const int wkey = (st_t & 7) << 4;

  f32x4 r0, r1, r2, r3;
  auto issue = [&](int st) {
    const float* p = xrow0 + (long)st * 16 * NF + st_c0 * 4 * 64;
    r0 = *(const f32x4*)(p);
    r1 = *(const f32x4*)(p + 64);
    r2 = *(const f32x4*)(p + 128);
    r3 = *(const f32x4*)(p + 192);
  };
  auto stageX = [&](char* X) {
    #pragma unroll
    for (int e = 0; e < 4; ++e) {
      int p = st_dq * 4 + e;
      unsigned lo = (unsigned)f2bf(r0[e]) | ((unsigned)f2bf(r1[e]) << 16);
      unsigned hi = (unsigned)f2bf(r2[e]) | ((unsigned)f2bf(r3[e]) << 16);
      *(u32x2*)(X + p * 2048 + st_t * 128 + ((st_c0 * 8) ^ wkey)) = u32x2{lo, hi};
    }
  };

  issue(0);
  stageX(Xb0);
  issue(1);
  __syncthreads();

  const int rkey = (l15 & 7) << 4;
  const int ct = tid & 15, cb0 = tid >> 4;       // copy-out map: (t, b-base)

  for (int st = 0; st < 8; ++st) {
    char* const Xc = (st & 1) ? Xb1 : Xb0;
    char* const Xn = (st & 1) ? Xb0 : Xb1;
    char* const Yc = (st & 1) ? Yb1 : Yb0;

    const char* Xs = Xc + wv * 2048 + l15 * 128;
    bf16x8 bx0 = *(const bf16x8*)(Xs + ((0  + lq * 16) ^ rkey));
    bf16x8 bx1 = *(const bf16x8*)(Xs + ((64 + lq * 16) ^ rkey));
    f32x4 acc[4];
    #pragma unroll
    for (int bt = 0; bt < 4; ++bt) {
      acc[bt] = __builtin_amdgcn_mfma_f32_16x16x32_bf16(fA[bt][0], bx0, (f32x4){0.f,0.f,0.f,0.f}, 0, 0, 0);
      acc[bt] = __builtin_amdgcn_mfma_f32_16x16x32_bf16(fA[bt][1], bx1, acc[bt], 0, 0, 0);
    }

    // Ybuf write: lane's 4 consecutive b packed -> u32x2; banks 2-way (free)
    {
      char* Yw = Yc + l15 * 1044 + wv * 128 + lq * 8;
      #pragma unroll
      for (int bt = 0; bt < 4; ++bt) {
        unsigned lo = (unsigned)f2bf(acc[bt][0]) | ((unsigned)f2bf(acc[bt][1]) << 16);
        unsigned hi = (unsigned)f2bf(acc[bt][2]) | ((unsigned)f2bf(acc[bt][3]) << 16);
        *(u32x2*)(Yw + bt * 32) = u32x2{lo, hi};
      }
    }

    stageX(Xn);
    issue(st + 2 <= 7 ? st + 2 : 7);
    __syncthreads();

    // copy-out: y token-major; (b,t) 16B d-chunk -> t*8192 + b*128 + dg*16.
    // Line (128B) completed by the 8 dg-siblings on the same XCD.
    #pragma unroll
    for (int h = 0; h < 2; ++h) {
      const int b = cb0 + h * 32;
      const char* Ys = Yc + ct * 1044 + b * 2;
      unsigned short hv[8];
      #pragma unroll
      for (int j = 0; j < 8; ++j) hv[j] = *(const unsigned short*)(Ys + j * 128);
      u32x4 wq;
      #pragma unroll
      for (int m = 0; m < 4; ++m)
        wq[m] = (unsigned)hv[2 * m] | ((unsigned)hv[2 * m + 1] << 16);
      *(u32x4*)((char*)yp + (T0 + st * 16 + ct) * 8192 + b * 128 + dg * 16) = wq;
    }
  }
}

// ---------------- stage 2 v10: token-major 64B-dense reads; LDS/barrier-free -------
// block: 512 thr = 8 waves; wave wv owns a = ag*8+wv; 128 tokens as 8 tiles of 16.
// B-frag = y[t][a*64 + kh*32 + lq*8]: per instr 16 rows x 64B contiguous.
__global__ __launch_bounds__(512, 4) void ks2(
    const unsigned short* __restrict__ yp, const unsigned short* __restrict__ f1s,
    const float* __restrict__ bias, float* __restrict__ out, int tbase)
{
  const int bid = blockIdx.x;                 // 0..511 per slice
  const int ag  = bid & 7;
  const long T0 = (long)tbase + (long)(bid >> 3) * 128;

  const int tid = threadIdx.x, lane = tid & 63, wv = tid >> 6;
  const int l15 = lane & 15, lq = lane >> 4;
  const int a = ag * 8 + wv;

  bf16x8 fa[4][2];
  #pragma unroll
  for (int bt = 0; bt < 4; ++bt)
    #pragma unroll
    for (int kh = 0; kh < 2; ++kh)
      fa[bt][kh] = *(const bf16x8*)(f1s + (size_t)a * 4096 + (bt * 16 + l15) * 64 + kh * 32 + lq * 8);
  f32x4 bv[4];
  #pragma unroll
  for (int bt = 0; bt < 4; ++bt)
    bv[bt] = *(const f32x4*)(bias + a * 64 + bt * 16 + lq * 4);

  // y base: token row (T0+l15), feature offset a*64 + lq*8 (kh adds 32 elems = 64B)
  const char* const yb = (const char*)yp + (T0 + l15) * 8192 + a * 128 + lq * 16;
  float* const ob = out + (T0 + l15) * (size_t)NF + a * 64 + lq * 4;

  auto compute = [&](int j, bf16x8 c0, bf16x8 c1) {
    f32x4 acc[4];
    #pragma unroll
    for (int bt = 0; bt < 4; ++bt) {
      acc[bt] = __builtin_amdgcn_mfma_f32_16x16x32_bf16(fa[bt][0], c0, (f32x4){0.f,0.f,0.f,0.f}, 0, 0, 0);
      acc[bt] = __builtin_amdgcn_mfma_f32_16x16x32_bf16(fa[bt][1], c1, acc[bt], 0, 0, 0);
    }
    float* op = ob + (size_t)j * 16 * NF;
    #pragma unroll
    for (int bt = 0; bt < 4; ++bt) {
      f32x4 r = acc[bt] + bv[bt];
      __builtin_nontemporal_store(r, (f32x4*)(op + bt * 16));
    }
  };

  // depth-2 named-register pipeline over 8 tiles of 16 tokens (tile = 128KB rows)
  bf16x8 A0 = *(const bf16x8*)(yb);
  bf16x8 A1 = *(const bf16x8*)(yb + 64);
  bf16x8 B0 = *(const bf16x8*)(yb + 131072);
  bf16x8 B1 = *(const bf16x8*)(yb + 131072 + 64);

  #pragma unroll
  for (int j = 0; j < 8; j += 2) {
    bf16x8 nA0 = A0, nA1 = A1, nB0 = B0, nB1 = B1;
    if (j + 2 < 8) {
      nA0 = *(const bf16x8*)(yb + (size_t)(j + 2) * 131072);
      nA1 = *(const bf16x8*)(yb + (size_t)(j + 2) * 131072 + 64);
    }
    compute(j, A0, A1);
    if (j + 3 < 8) {
      nB0 = *(const bf16x8*)(yb + (size_t)(j + 3) * 131072);
      nB1 = *(const bf16x8*)(yb + (size_t)(j + 3) * 131072 + 64);
    }
    compute(j + 1, B0, B1);
    A0 = nA0; A1 = nA1; B0 = nB0; B1 = nB1;
  }
}

// ---------------- naive fp32 fallback (only if workspace too small) ----------------
__global__ void ks_naive(const float* __restrict__ x, const float* __restrict__ f0,
                         const float* __restrict__ f1, const float* __restrict__ bias,
                         float* __restrict__ out)
{
  __shared__ float xr[4096];
  __shared__ float yr[4096];
  long t = blockIdx.x;
  int tid = threadIdx.x;
  for (int i = tid; i < 4096; i += 256) xr[i] = x[t * 4096 + i];
  __syncthreads();
  for (int i = tid; i < 4096; i += 256) {
    int b = i >> 6, d = i & 63;
    float s = 0.f;
    for (int c = 0; c < 64; ++c) s += xr[c * 64 + d] * f0[(b * 64 + c) * 64 + d];
    yr[i] = s;
  }
  __syncthreads();
  for (int i = tid; i < 4096; i += 256) {
    int a = i >> 6;
    float s = bias[i];
    for (int c = 0; c < 64; ++c) s += yr[a * 64 + c] * f1[(size_t)i * 64 + c];
    out[t * 4096 + i] = s;
  }
}

extern "C" void kernel_launch(void* const* d_in, const int* in_sizes, int n_in,
                              void* d_out, int out_size, void* d_ws, size_t ws_size,
                              hipStream_t stream) {
  const float* x    = (const float*)d_in[0];
  const float* f0   = (const float*)d_in[1];
  const float* f1   = (const float*)d_in[2];
  const float* bias = (const float*)d_in[3];
  float* out = (float*)d_out;

  const size_t ybytes = (size_t)NT * NF * 2;          // 128 MB bf16 intermediate
  const size_t fbytes = (size_t)64 * 64 * 64 * 2;     // 512 KB per factor
  if (ws_size >= ybytes + 2 * fbytes) {
    unsigned short* yw  = (unsigned short*)d_ws;
    unsigned short* f0s = yw + (size_t)NT * NF;
    unsigned short* f1s = f0s + 64 * 64 * 64;
    ks_prep<<<2048, 256, 0, stream>>>(f0, f1, f0s, f1s);
    for (int s = 0; s < NT / SLICE; ++s) {
      ks1<<<(SLICE / 128) * 8, 512, 0, stream>>>(x, f0s, yw, s * SLICE);
      ks2<<<(SLICE / 128) * 8, 512, 0, stream>>>(yw, f1s, bias, out, s * SLICE);
    }
  } else {
    ks_naive<<<NT, 256, 0, stream>>>(x, f0, f1, bias, out);
  }
}